// Round 1
// baseline (287.772 us; speedup 1.0000x reference)
//
#include <hip/hip_runtime.h>

constexpr int NPIX = 9216;   // 96*96
constexpr int IMW  = 96;
constexpr int BJ   = 576;    // j's per block (= block threads, 9 waves)
constexpr int SI   = 288;    // i's per segment (staged in LDS)
constexpr int NSEG = 32;     // 9216/288
constexpr int NJB  = 16;     // 9216/576

constexpr float LCLIP = 18.420681f;  // -log(1e-8)

__global__ void k_init(const int* __restrict__ mask, float* __restrict__ du,
                       float* __restrict__ q){
    int j = blockIdx.x * 256 + threadIdx.x;
    if (j < NPIX){
        float d = (mask[j] == 0) ? LCLIP : -LCLIP;
        du[j] = d;
        q[j]  = 1.0f / (1.0f + __expf(d));   // initial Q[0]
    }
}

// partial matvec: pmsg[seg][j] = sum_{i in seg} q[i]*K[i,j]  (K includes diag=13; removed later)
template<bool KSUM>
__global__ __launch_bounds__(BJ) void k_matvec(const float* __restrict__ img,
                                               const float* __restrict__ q,
                                               float* __restrict__ pmsg,
                                               float* __restrict__ pksum){
    __shared__ float4 st[SI];
    const int tid = threadIdx.x;
    const int j   = blockIdx.x * BJ + tid;
    const int seg = blockIdx.y;

    if (tid < SI){
        int i = seg * SI + tid;
        st[tid] = make_float4((float)(i % IMW), (float)(i / IMW), img[i], q[i]);
    }
    const float xj = (float)(j % IMW);
    const float yj = (float)(j / IMW);
    const float fj = img[j];
    __syncthreads();

    float acc1 = 0.f, acc2 = 0.f, ak1 = 0.f, ak2 = 0.f;
    #pragma unroll 4
    for (int u = 0; u < SI; ++u){
        float4 s = st[u];
        float dx = s.x - xj;
        float dy = s.y - yj;
        float df = s.z - fj;
        float d2 = dx*dx + dy*dy;
        float a1 = d2 * (-1.0f/18.0f);                               // gaussian: sxy=3
        float a2 = d2 * (-1.0f/5000.0f) + (df*df) * (-1.0f/400.0f);  // bilateral: sxy=50, srgb=20 (df2=2*Δf²)
        float e1 = __expf(a1);
        float e2 = __expf(a2);
        acc1 += s.w * e1;
        acc2 += s.w * e2;
        if (KSUM){ ak1 += e1; ak2 += e2; }
    }
    pmsg[seg * NPIX + j] = 3.0f*acc1 + 10.0f*acc2;
    if (KSUM) pksum[seg * NPIX + j] = 3.0f*ak1 + 10.0f*ak2;
}

// MODE: 0 = first iter (reduce ksum too, write q), 1 = mid (write q), 2 = last (write pred)
template<int MODE>
__global__ void k_update(const float* __restrict__ pmsg, const float* __restrict__ pksum,
                         const float* __restrict__ du, float* __restrict__ ksum,
                         float* __restrict__ q, float* __restrict__ out){
    int j = blockIdx.x * 256 + threadIdx.x;
    if (j >= NPIX) return;
    float m = 0.f;
    for (int s = 0; s < NSEG; ++s) m += pmsg[s * NPIX + j];
    float K;
    if (MODE == 0){
        K = 0.f;
        for (int s = 0; s < NSEG; ++s) K += pksum[s * NPIX + j];
        K -= 13.0f;                    // remove diagonal from Ksum
        ksum[j] = K;
    } else {
        K = ksum[j];
    }
    m -= 13.0f * q[j];                 // remove diagonal q[j]*K[j,j]
    float delta = du[j] + K - 2.0f*m;  // logit(label1) - logit(label0)... (Q0 = sigmoid(-delta))
    if (MODE == 2){
        out[j] = (delta > 0.f) ? 1.0f : 0.0f;   // argmax; tie -> label 0
    } else {
        q[j] = 1.0f / (1.0f + __expf(delta));
    }
}

extern "C" void kernel_launch(void* const* d_in, const int* in_sizes, int n_in,
                              void* d_out, int out_size, void* d_ws, size_t ws_size,
                              hipStream_t stream){
    const float* img  = (const float*)d_in[0];
    const int*   mask = (const int*)d_in[1];
    float* out = (float*)d_out;
    float* ws  = (float*)d_ws;

    float* q     = ws;
    float* du    = ws + NPIX;
    float* ksum  = ws + 2*NPIX;
    float* pmsg  = ws + 3*NPIX;
    float* pksum = ws + 3*NPIX + (size_t)NSEG*NPIX;

    dim3 g1(36), b1(256);
    dim3 gm(NJB, NSEG), bm(BJ);

    k_init<<<g1, b1, 0, stream>>>(mask, du, q);

    // iter 1 (also computes Ksum)
    k_matvec<true ><<<gm, bm, 0, stream>>>(img, q, pmsg, pksum);
    k_update<0><<<g1, b1, 0, stream>>>(pmsg, pksum, du, ksum, q, out);
    // iters 2..4
    for (int it = 0; it < 3; ++it){
        k_matvec<false><<<gm, bm, 0, stream>>>(img, q, pmsg, pksum);
        k_update<1><<<g1, b1, 0, stream>>>(pmsg, pksum, du, ksum, q, out);
    }
    // iter 5 -> prediction
    k_matvec<false><<<gm, bm, 0, stream>>>(img, q, pmsg, pksum);
    k_update<2><<<g1, b1, 0, stream>>>(pmsg, pksum, du, ksum, q, out);
}

// Round 2
// 220.091 us; speedup vs baseline: 1.3075x; 1.3075x over previous
//
#include <hip/hip_runtime.h>

constexpr int NPIX = 9216;   // 96*96
constexpr int IMW  = 96;
constexpr int NSEG = 32;     // segments of i
constexpr int SI   = 288;    // i's per segment (3 rows)
constexpr int NJB  = 36;     // 9216/256 j-blocks

constexpr float LCLIP = 18.420681f;              // -log(1e-8)
constexpr float LOG2E = 1.4426950408889634f;
constexpr float C1 = -LOG2E / 18.0f;             // gaussian spatial (sxy=3), base-2
constexpr float C2 = -LOG2E / 5000.0f;           // bilateral spatial (sxy=50), base-2
constexpr float C3 = -LOG2E / 400.0f;            // bilateral feature (2*df^2/(2*20^2)), base-2

// init unary delta + initial Q0; block 0 also builds the 1D gaussian row-sum table S
__global__ void k_init(const int* __restrict__ mask, float* __restrict__ du,
                       float* __restrict__ q, float* __restrict__ S){
    int j = blockIdx.x * 256 + threadIdx.x;
    if (j < NPIX){
        float d = (mask[j] == 0) ? LCLIP : -LCLIP;
        du[j] = d;
        q[j]  = 1.0f / (1.0f + __expf(d));
    }
    if (blockIdx.x == 0 && threadIdx.x < IMW){
        float t = (float)threadIdx.x;
        float acc = 0.f;
        for (int xp = 0; xp < IMW; ++xp){
            float dd = t - (float)xp;
            acc += exp2f(C1 * dd * dd);
        }
        S[threadIdx.x] = acc;   // sum_x' exp(-(t-x')^2/18)
    }
}

// separable gaussian, horizontal pass: gH[y][x] = sum_x' q[y][x'] * g(x-x')
__global__ __launch_bounds__(256) void k_gaussH(const float* __restrict__ q,
                                                float* __restrict__ gH){
    int j = blockIdx.x * 256 + threadIdx.x;
    int y = j / IMW, x = j % IMW;
    const float* row = q + y * IMW;
    float dxf = -(float)x;
    float acc = 0.f;
    #pragma unroll 8
    for (int xp = 0; xp < IMW; ++xp){
        float w = exp2f(C1 * dxf * dxf);
        acc = fmaf(row[xp], w, acc);
        dxf += 1.f;
    }
    gH[j] = acc;
}

// separable gaussian, vertical pass: gV[y][x] = sum_y' gH[y'][x] * g(y-y')
__global__ __launch_bounds__(256) void k_gaussV(const float* __restrict__ gH,
                                                float* __restrict__ gV){
    int j = blockIdx.x * 256 + threadIdx.x;
    int y = j / IMW, x = j % IMW;
    float dyf = -(float)y;
    float acc = 0.f;
    #pragma unroll 8
    for (int yp = 0; yp < IMW; ++yp){
        float w = exp2f(C1 * dyf * dyf);
        acc = fmaf(gH[yp * IMW + x], w, acc);
        dyf += 1.f;
    }
    gV[j] = acc;   // full gaussian message incl. diagonal
}

// dense bilateral partial matvec: pmsg[seg][j] = sum_{i in seg} q[i]*exp(-d2/5000 - df^2/400)
template<bool KSUM>
__global__ __launch_bounds__(256) void k_bilat(const float* __restrict__ img,
                                               const float* __restrict__ q,
                                               float* __restrict__ pmsg,
                                               float* __restrict__ pksum){
    __shared__ float2 st[SI];
    const int tid = threadIdx.x;
    const int j   = blockIdx.x * 256 + tid;
    const int seg = blockIdx.y;
    const int i0  = seg * SI;

    st[tid] = make_float2(img[i0 + tid], q[i0 + tid]);
    if (tid < SI - 256)
        st[256 + tid] = make_float2(img[i0 + 256 + tid], q[i0 + 256 + tid]);

    const float xj = (float)(j % IMW);
    const float yj = (float)(j / IMW);
    const float fj = img[j];
    __syncthreads();

    float acc = 0.f, ak = 0.f;
    const int r0 = seg * 3;           // SI = 3 rows
    for (int r = 0; r < 3; ++r){
        float dy = (float)(r0 + r) - yj;
        float b  = C2 * dy * dy;      // hoisted per row
        float dxf = -xj;
        #pragma unroll 8
        for (int x = 0; x < IMW; ++x){
            float2 s = st[r * IMW + x];      // wave-uniform broadcast
            float a  = fmaf(dxf * dxf, C2, b);
            float df = s.x - fj;
            a = fmaf(df * df, C3, a);
            float e = exp2f(a);
            acc = fmaf(s.y, e, acc);
            if (KSUM) ak += e;
            dxf += 1.f;
        }
    }
    pmsg[seg * NPIX + j] = acc;
    if (KSUM) pksum[seg * NPIX + j] = ak;
}

// MODE: 0 = first iter (build ksum, write q), 1 = mid (write q), 2 = last (write pred)
template<int MODE>
__global__ void k_update(const float* __restrict__ pmsg, const float* __restrict__ pksum,
                         const float* __restrict__ gV, const float* __restrict__ S,
                         const float* __restrict__ du, float* __restrict__ ksum,
                         float* __restrict__ q, float* __restrict__ out){
    int j = blockIdx.x * 256 + threadIdx.x;
    if (j >= NPIX) return;
    float B = 0.f;
    for (int s = 0; s < NSEG; ++s) B += pmsg[s * NPIX + j];
    float K;
    if (MODE == 0){
        float Bk = 0.f;
        for (int s = 0; s < NSEG; ++s) Bk += pksum[s * NPIX + j];
        float Gk = S[j % IMW] * S[j / IMW];      // separable gaussian row-sum product
        K = 3.0f * Gk + 10.0f * Bk - 13.0f;      // remove diagonal (3+10)
        ksum[j] = K;
    } else {
        K = ksum[j];
    }
    float m = 3.0f * gV[j] + 10.0f * B - 13.0f * q[j];   // remove diagonal q_j*13
    float delta = du[j] + K - 2.0f * m;                   // logit(1) - logit(0)
    if (MODE == 2){
        out[j] = (delta > 0.f) ? 1.0f : 0.0f;
    } else {
        q[j] = 1.0f / (1.0f + __expf(delta));
    }
}

extern "C" void kernel_launch(void* const* d_in, const int* in_sizes, int n_in,
                              void* d_out, int out_size, void* d_ws, size_t ws_size,
                              hipStream_t stream){
    const float* img  = (const float*)d_in[0];
    const int*   mask = (const int*)d_in[1];
    float* out = (float*)d_out;
    float* ws  = (float*)d_ws;

    float* q     = ws;
    float* du    = q    + NPIX;
    float* ksum  = du   + NPIX;
    float* gH    = ksum + NPIX;
    float* gV    = gH   + NPIX;
    float* S     = gV   + NPIX;          // 96 (pad to 128)
    float* pmsg  = S    + 128;
    float* pksum = pmsg + (size_t)NSEG * NPIX;

    dim3 g1(NJB), b1(256);
    dim3 gm(NJB, NSEG), bm(256);

    k_init<<<g1, b1, 0, stream>>>(mask, du, q, S);

    // iter 1 (also computes Ksum)
    k_gaussH<<<g1, b1, 0, stream>>>(q, gH);
    k_gaussV<<<g1, b1, 0, stream>>>(gH, gV);
    k_bilat<true ><<<gm, bm, 0, stream>>>(img, q, pmsg, pksum);
    k_update<0><<<g1, b1, 0, stream>>>(pmsg, pksum, gV, S, du, ksum, q, out);
    // iters 2..4
    for (int it = 0; it < 3; ++it){
        k_gaussH<<<g1, b1, 0, stream>>>(q, gH);
        k_gaussV<<<g1, b1, 0, stream>>>(gH, gV);
        k_bilat<false><<<gm, bm, 0, stream>>>(img, q, pmsg, pksum);
        k_update<1><<<g1, b1, 0, stream>>>(pmsg, pksum, gV, S, du, ksum, q, out);
    }
    // iter 5 -> prediction
    k_gaussH<<<g1, b1, 0, stream>>>(q, gH);
    k_gaussV<<<g1, b1, 0, stream>>>(gH, gV);
    k_bilat<false><<<gm, bm, 0, stream>>>(img, q, pmsg, pksum);
    k_update<2><<<g1, b1, 0, stream>>>(pmsg, pksum, gV, S, du, ksum, q, out);
}